// Round 1
// 408.715 us; speedup vs baseline: 1.0652x; 1.0652x over previous
//
#include <hip/hip_runtime.h>
#include <hip/hip_bf16.h>

typedef __bf16 bf16;
typedef unsigned int u32;
typedef __attribute__((ext_vector_type(8))) __bf16 bf16x8;
typedef __attribute__((ext_vector_type(4))) float f32x4;

#define Bsz 256
#define Tsz 256
#define Csz 384
#define Hn  6
#define Dh  64
#define NQKV 1152   // 3 mats * 6 heads * 64

#define MFMA16(a, b, c) __builtin_amdgcn_mfma_f32_16x16x32_bf16(a, b, c, 0, 0, 0)

typedef __attribute__((address_space(3))) u32 lds_u32;
typedef __attribute__((address_space(1))) const u32 gbl_u32;
__device__ __forceinline__ void gl2lds16(const void* g, void* l) {
    // async global->LDS, 16B/lane; LDS dest = wave-uniform base + lane*16
    __builtin_amdgcn_global_load_lds((gbl_u32*)g, (lds_u32*)l, 16, 0, 0);
}

__device__ __forceinline__ float redmax16(float x) {
    x = fmaxf(x, __shfl_xor(x, 1));
    x = fmaxf(x, __shfl_xor(x, 2));
    x = fmaxf(x, __shfl_xor(x, 4));
    x = fmaxf(x, __shfl_xor(x, 8));
    return x;
}
__device__ __forceinline__ float redsum16(float x) {
    x += __shfl_xor(x, 1);
    x += __shfl_xor(x, 2);
    x += __shfl_xor(x, 4);
    x += __shfl_xor(x, 8);
    return x;
}

// ---------------- x: fp32 -> bf16 ----------------
__global__ __launch_bounds__(256) void convert_x(
    const float* __restrict__ x, bf16* __restrict__ xb)
{
    size_t i = ((size_t)blockIdx.x * 256 + threadIdx.x) * 8;
    float4 f0 = *(const float4*)&x[i];
    float4 f1 = *(const float4*)&x[i + 4];
    bf16x8 o;
    o[0] = (bf16)f0.x; o[1] = (bf16)f0.y; o[2] = (bf16)f0.z; o[3] = (bf16)f0.w;
    o[4] = (bf16)f1.x; o[5] = (bf16)f1.y; o[6] = (bf16)f1.z; o[7] = (bf16)f1.w;
    *(bf16x8*)&xb[i] = o;
}

// ---------------- weights: fp32 -> bf16, B^T [n][k] layout ----------------
// Btqkv[n][k], n = wi*384 + h*64 + d, k = c. Bpt[n][k] = Wp[k][n]. Tiny (2.4MB).
__global__ __launch_bounds__(384) void prep_w(
    const float* __restrict__ Wq, const float* __restrict__ Wk,
    const float* __restrict__ Wv, const float* __restrict__ Wp,
    bf16* __restrict__ Btqkv, bf16* __restrict__ Bpt)
{
    const int n = blockIdx.x, k = threadIdx.x;
    if (n < NQKV) {
        int wi = n / Csz, rem = n - wi * Csz, h = rem >> 6, d = rem & 63;
        const float* W = wi == 0 ? Wq : (wi == 1 ? Wk : Wv);
        Btqkv[(size_t)n * Csz + k] = (bf16)W[((size_t)h * Csz + k) * Dh + d];
    } else {
        int n2 = n - NQKV;
        Bpt[(size_t)n2 * Csz + k] = (bf16)Wp[(size_t)k * Csz + n2];
    }
}

// ---------------- QKV as one 65536x1152x384 GEMM (m97 structure) ----------------
// 128x128 tile, BK=64, global_load_lds width16, 2-barrier K-loop.
// Grid is 1D-linearized with n-tile fastest + bijective XCD-chunk swizzle:
//   consecutive blocks on one XCD sweep all 9 n-tiles of one A-panel (98 KB,
//   L2-resident) before moving to the next panel -> A fetched from HBM ~once.
__global__ __launch_bounds__(256) void qkv_gemm(
    const bf16* __restrict__ A, const bf16* __restrict__ Bt,
    bf16* __restrict__ q, bf16* __restrict__ k, bf16* __restrict__ v)
{
    __shared__ bf16 As[128][64];
    __shared__ bf16 Bs[128][64];
    const int tid = threadIdx.x, w = tid >> 6, lane = tid & 63;
    const int l4 = lane & 15, quad = lane >> 4;
    const int wm = w & 1, wn = w >> 1;

    // XCD-chunked bijective swizzle (nwg = 4608 = 8 * 576; 576 = 64 panels * 9)
    const int NT = NQKV / 128;                      // 9 n-tiles
    const int nwg = (Bsz * Tsz / 128) * NT;         // 4608
    const int orig = blockIdx.x;
    const int wg = (orig & 7) * (nwg >> 3) + (orig >> 3);
    const int mt_ = wg / NT;
    const int nt_ = wg - mt_ * NT;
    const int m0 = mt_ * 128, n0 = nt_ * 128;

    const int srow = lane >> 3;          // 0..7 within an issue's 8 rows
    const int skk  = (lane & 7) * 8;     // k-elem offset (16B chunk)

    f32x4 acc[4][4] = {};

    for (int kc = 0; kc < Csz / 64; ++kc) {
        #pragma unroll
        for (int i = 0; i < 4; ++i) {
            int r = (w * 4 + i) * 8 + srow;
            gl2lds16(&A [(size_t)(m0 + r) * Csz + kc * 64 + skk],
                     (char*)&As[0][0] + (w * 4 + i) * 1024);
            gl2lds16(&Bt[(size_t)(n0 + r) * Csz + kc * 64 + skk],
                     (char*)&Bs[0][0] + (w * 4 + i) * 1024);
        }
        __syncthreads();
        #pragma unroll
        for (int ks = 0; ks < 2; ++ks) {
            bf16x8 af[4], bfr[4];
            #pragma unroll
            for (int mt = 0; mt < 4; ++mt)
                af[mt] = *(const bf16x8*)&As[wm * 64 + mt * 16 + l4][ks * 32 + quad * 8];
            #pragma unroll
            for (int nt = 0; nt < 4; ++nt)
                bfr[nt] = *(const bf16x8*)&Bs[wn * 64 + nt * 16 + l4][ks * 32 + quad * 8];
            #pragma unroll
            for (int mt = 0; mt < 4; ++mt)
                #pragma unroll
                for (int nt = 0; nt < 4; ++nt)
                    acc[mt][nt] = MFMA16(af[mt], bfr[nt], acc[mt][nt]);
        }
        __syncthreads();
    }

    #pragma unroll
    for (int nt = 0; nt < 4; ++nt) {
        int n = n0 + wn * 64 + nt * 16 + l4;
        int wi = n / Csz, rem = n - wi * Csz;
        int h = rem >> 6, d = rem & 63;
        bf16* outp = wi == 0 ? q : (wi == 1 ? k : v);
        #pragma unroll
        for (int mt = 0; mt < 4; ++mt)
            #pragma unroll
            for (int r = 0; r < 4; ++r) {
                int m = m0 + wm * 64 + mt * 16 + quad * 4 + r;
                int b = m >> 8, t = m & 255;
                outp[(((size_t)(b * Hn + h)) * Tsz + t) * Dh + d] = (bf16)acc[mt][nt][r];
            }
    }
}

// ---------------- Flash attention, MFMA (exp2-domain softmax) ----------------
__global__ __launch_bounds__(256) void attn_mfma(
    const bf16* __restrict__ q, const bf16* __restrict__ k, const bf16* __restrict__ v,
    bf16* __restrict__ att)
{
    __shared__ bf16 Kl[64][72];
    __shared__ bf16 Vt[64][72];      // [d][s]
    __shared__ bf16 Pl[4][16][72];   // per-wave [qrow][s]
    const float SCL = 0.18033688f;   // 0.125 * log2(e)
    const int tid = threadIdx.x, w = tid >> 6, lane = tid & 63;
    const int l4 = lane & 15, quad = lane >> 4;

    // XCD-chunked swizzle (nblk = 6144 = 8 * 768): the 4 qt-blocks of one
    // (b,h) stay on one XCD -> K/V L2 reuse across causal tiles.
    const int orig = blockIdx.x;
    const int blk = (orig & 7) * 768 + (orig >> 3);
    const int bh = blk >> 2, qt = blk & 3;
    const int b = bh / Hn, h = bh % Hn;
    const bf16* qb = q + (size_t)bh * Tsz * Dh;
    const bf16* kb = k + (size_t)bh * Tsz * Dh;
    const bf16* vb = v + (size_t)bh * Tsz * Dh;

    const int trow = qt * 64 + w * 16 + l4;
    const bf16x8 qa0 = *(const bf16x8*)&qb[trow * Dh + quad * 8];
    const bf16x8 qa1 = *(const bf16x8*)&qb[trow * Dh + 32 + quad * 8];

    f32x4 o[4] = {f32x4{0,0,0,0}, f32x4{0,0,0,0}, f32x4{0,0,0,0}, f32x4{0,0,0,0}};
    float mrun[4] = {-3.0e38f, -3.0e38f, -3.0e38f, -3.0e38f};
    float lrun[4] = {0.f, 0.f, 0.f, 0.f};

    for (int kt = 0; kt <= qt; ++kt) {
        #pragma unroll
        for (int it = 0; it < 2; ++it) {
            int idx = it * 256 + tid;
            int s = idx >> 3, d8 = (idx & 7) * 8;
            *(bf16x8*)&Kl[s][d8] = *(const bf16x8*)&kb[(kt * 64 + s) * Dh + d8];
        }
        #pragma unroll
        for (int it = 0; it < 2; ++it) {
            int idx = it * 256 + tid;
            int s = idx & 63, d8 = (idx >> 6) * 8;
            bf16x8 vv = *(const bf16x8*)&vb[(kt * 64 + s) * Dh + d8];
            #pragma unroll
            for (int j = 0; j < 8; ++j) Vt[d8 + j][s] = vv[j];
        }
        __syncthreads();

        f32x4 sc[4] = {f32x4{0,0,0,0}, f32x4{0,0,0,0}, f32x4{0,0,0,0}, f32x4{0,0,0,0}};
        #pragma unroll
        for (int nt = 0; nt < 4; ++nt) {
            bf16x8 b0 = *(const bf16x8*)&Kl[nt * 16 + l4][quad * 8];
            bf16x8 b1 = *(const bf16x8*)&Kl[nt * 16 + l4][32 + quad * 8];
            sc[nt] = MFMA16(qa0, b0, sc[nt]);
            sc[nt] = MFMA16(qa1, b1, sc[nt]);
        }

        float mnew[4], alpha[4];
        #pragma unroll
        for (int r = 0; r < 4; ++r) {
            int tg = qt * 64 + w * 16 + quad * 4 + r;
            float mx = mrun[r];
            #pragma unroll
            for (int nt = 0; nt < 4; ++nt) {
                float sv = sc[nt][r] * SCL;        // log2-domain
                int sg = kt * 64 + nt * 16 + l4;
                if (sg > tg) sv = -1.0e30f;
                sc[nt][r] = sv;
                mx = fmaxf(mx, sv);
            }
            mx = redmax16(mx);
            mnew[r] = mx;
            alpha[r] = __builtin_amdgcn_exp2f(mrun[r] - mx);
            mrun[r] = mx;
        }
        #pragma unroll
        for (int r = 0; r < 4; ++r) {
            float sm = 0.f;
            #pragma unroll
            for (int nt = 0; nt < 4; ++nt) {
                float e = __builtin_amdgcn_exp2f(sc[nt][r] - mnew[r]);
                sc[nt][r] = e;
                sm += e;
            }
            sm = redsum16(sm);
            lrun[r] = lrun[r] * alpha[r] + sm;
        }
        #pragma unroll
        for (int nt = 0; nt < 4; ++nt)
            #pragma unroll
            for (int r = 0; r < 4; ++r) o[nt][r] *= alpha[r];

        #pragma unroll
        for (int nt = 0; nt < 4; ++nt)
            #pragma unroll
            for (int r = 0; r < 4; ++r)
                Pl[w][quad * 4 + r][nt * 16 + l4] = (bf16)sc[nt][r];

        bf16x8 pa0 = *(const bf16x8*)&Pl[w][l4][quad * 8];
        bf16x8 pa1 = *(const bf16x8*)&Pl[w][l4][32 + quad * 8];
        #pragma unroll
        for (int nt = 0; nt < 4; ++nt) {
            bf16x8 vb0 = *(const bf16x8*)&Vt[nt * 16 + l4][quad * 8];
            bf16x8 vb1 = *(const bf16x8*)&Vt[nt * 16 + l4][32 + quad * 8];
            o[nt] = MFMA16(pa0, vb0, o[nt]);
            o[nt] = MFMA16(pa1, vb1, o[nt]);
        }
        __syncthreads();
    }

    #pragma unroll
    for (int r = 0; r < 4; ++r) {
        float inv = 1.f / lrun[r];
        int tg = qt * 64 + w * 16 + quad * 4 + r;
        #pragma unroll
        for (int nt = 0; nt < 4; ++nt)
            att[((size_t)(b * Tsz + tg)) * Csz + h * Dh + nt * 16 + l4] =
                (bf16)(o[nt][r] * inv);
    }
}

// ---------------- Output projection as 65536x384x384 GEMM ----------------
__global__ __launch_bounds__(256) void proj_gemm(
    const bf16* __restrict__ A, const bf16* __restrict__ Bt,
    const float* __restrict__ bias, float* __restrict__ out)
{
    __shared__ bf16 As[128][64];
    __shared__ bf16 Bs[128][64];
    const int tid = threadIdx.x, w = tid >> 6, lane = tid & 63;
    const int l4 = lane & 15, quad = lane >> 4;
    const int wm = w & 1, wn = w >> 1;

    // XCD-chunked swizzle (nwg = 1536 = 8 * 192; 192 = 64 panels * 3 n-tiles)
    const int NT = Csz / 128;                       // 3
    const int nwg = (Bsz * Tsz / 128) * NT;         // 1536
    const int orig = blockIdx.x;
    const int wg = (orig & 7) * (nwg >> 3) + (orig >> 3);
    const int mt_ = wg / NT;
    const int nt_ = wg - mt_ * NT;
    const int m0 = mt_ * 128, n0 = nt_ * 128;

    const int srow = lane >> 3;
    const int skk  = (lane & 7) * 8;

    f32x4 acc[4][4] = {};

    for (int kc = 0; kc < Csz / 64; ++kc) {
        #pragma unroll
        for (int i = 0; i < 4; ++i) {
            int r = (w * 4 + i) * 8 + srow;
            gl2lds16(&A [(size_t)(m0 + r) * Csz + kc * 64 + skk],
                     (char*)&As[0][0] + (w * 4 + i) * 1024);
            gl2lds16(&Bt[(size_t)(n0 + r) * Csz + kc * 64 + skk],
                     (char*)&Bs[0][0] + (w * 4 + i) * 1024);
        }
        __syncthreads();
        #pragma unroll
        for (int ks = 0; ks < 2; ++ks) {
            bf16x8 af[4], bfr[4];
            #pragma unroll
            for (int mt = 0; mt < 4; ++mt)
                af[mt] = *(const bf16x8*)&As[wm * 64 + mt * 16 + l4][ks * 32 + quad * 8];
            #pragma unroll
            for (int nt = 0; nt < 4; ++nt)
                bfr[nt] = *(const bf16x8*)&Bs[wn * 64 + nt * 16 + l4][ks * 32 + quad * 8];
            #pragma unroll
            for (int mt = 0; mt < 4; ++mt)
                #pragma unroll
                for (int nt = 0; nt < 4; ++nt)
                    acc[mt][nt] = MFMA16(af[mt], bfr[nt], acc[mt][nt]);
        }
        __syncthreads();
    }

    #pragma unroll
    for (int nt = 0; nt < 4; ++nt) {
        int n = n0 + wn * 64 + nt * 16 + l4;
        float bv = bias[n];
        #pragma unroll
        for (int mt = 0; mt < 4; ++mt)
            #pragma unroll
            for (int r = 0; r < 4; ++r) {
                int m = m0 + wm * 64 + mt * 16 + quad * 4 + r;
                out[(size_t)m * Csz + n] = acc[mt][nt][r] + bv;
            }
    }
}

extern "C" void kernel_launch(void* const* d_in, const int* in_sizes, int n_in,
                              void* d_out, int out_size, void* d_ws, size_t ws_size,
                              hipStream_t stream)
{
    const float* x  = (const float*)d_in[0];
    const float* Wq = (const float*)d_in[1];
    const float* Wk = (const float*)d_in[2];
    const float* Wv = (const float*)d_in[3];
    const float* Wp = (const float*)d_in[4];
    const float* bp = (const float*)d_in[5];
    float* out = (float*)d_out;

    const size_t npe = (size_t)Bsz * Tsz * Csz;   // 25,165,824 elems
    bf16* xb    = (bf16*)d_ws;          // [65536,384]; reused as att after qkv
    bf16* att   = xb;                   // alias: xb dead once qkv_gemm completes
    bf16* q     = xb + npe;             // [B,H,T,D]
    bf16* k     = q  + npe;
    bf16* v     = k  + npe;
    bf16* Btqkv = v  + npe;             // [1152,384]
    bf16* Bpt   = Btqkv + (size_t)NQKV * Csz;   // [384,384]

    convert_x<<<npe / 2048, 256, 0, stream>>>(x, xb);
    prep_w<<<NQKV + Csz, 384, 0, stream>>>(Wq, Wk, Wv, Wp, Btqkv, Bpt);
    qkv_gemm<<<(Bsz * Tsz / 128) * (NQKV / 128), 256, 0, stream>>>(xb, Btqkv, q, k, v);
    attn_mfma<<<Bsz * Hn * 4, 256, 0, stream>>>(q, k, v, att);
    proj_gemm<<<(Bsz * Tsz / 128) * (Csz / 128), 256, 0, stream>>>(att, Bpt, bp, out);
}

// Round 2
// 387.491 us; speedup vs baseline: 1.1235x; 1.0548x over previous
//
#include <hip/hip_runtime.h>
#include <hip/hip_bf16.h>

typedef __bf16 bf16;
typedef unsigned int u32;
typedef __attribute__((ext_vector_type(8))) __bf16 bf16x8;
typedef __attribute__((ext_vector_type(4))) float f32x4;

#define Bsz 256
#define Tsz 256
#define Csz 384
#define Hn  6
#define Dh  64
#define NQKV 1152   // 3 mats * 6 heads * 64

#define MFMA16(a, b, c) __builtin_amdgcn_mfma_f32_16x16x32_bf16(a, b, c, 0, 0, 0)

typedef __attribute__((address_space(3))) u32 lds_u32;
typedef __attribute__((address_space(1))) const u32 gbl_u32;
__device__ __forceinline__ void gl2lds16(const void* g, void* l) {
    // async global->LDS, 16B/lane; LDS dest = wave-uniform base + lane*16
    __builtin_amdgcn_global_load_lds((gbl_u32*)g, (lds_u32*)l, 16, 0, 0);
}

__device__ __forceinline__ float redmax16(float x) {
    x = fmaxf(x, __shfl_xor(x, 1));
    x = fmaxf(x, __shfl_xor(x, 2));
    x = fmaxf(x, __shfl_xor(x, 4));
    x = fmaxf(x, __shfl_xor(x, 8));
    return x;
}
__device__ __forceinline__ float redsum16(float x) {
    x += __shfl_xor(x, 1);
    x += __shfl_xor(x, 2);
    x += __shfl_xor(x, 4);
    x += __shfl_xor(x, 8);
    return x;
}

// ---------------- x: fp32 -> bf16 ----------------
__global__ __launch_bounds__(256) void convert_x(
    const float* __restrict__ x, bf16* __restrict__ xb)
{
    size_t i = ((size_t)blockIdx.x * 256 + threadIdx.x) * 8;
    float4 f0 = *(const float4*)&x[i];
    float4 f1 = *(const float4*)&x[i + 4];
    bf16x8 o;
    o[0] = (bf16)f0.x; o[1] = (bf16)f0.y; o[2] = (bf16)f0.z; o[3] = (bf16)f0.w;
    o[4] = (bf16)f1.x; o[5] = (bf16)f1.y; o[6] = (bf16)f1.z; o[7] = (bf16)f1.w;
    *(bf16x8*)&xb[i] = o;
}

// ---------------- weights: fp32 -> bf16, B^T [n][k] layout ----------------
__global__ __launch_bounds__(384) void prep_w(
    const float* __restrict__ Wq, const float* __restrict__ Wk,
    const float* __restrict__ Wv, const float* __restrict__ Wp,
    bf16* __restrict__ Btqkv, bf16* __restrict__ Bpt)
{
    const int n = blockIdx.x, k = threadIdx.x;
    if (n < NQKV) {
        int wi = n / Csz, rem = n - wi * Csz, h = rem >> 6, d = rem & 63;
        const float* W = wi == 0 ? Wq : (wi == 1 ? Wk : Wv);
        Btqkv[(size_t)n * Csz + k] = (bf16)W[((size_t)h * Csz + k) * Dh + d];
    } else {
        int n2 = n - NQKV;
        Bpt[(size_t)n2 * Csz + k] = (bf16)Wp[(size_t)k * Csz + n2];
    }
}

// ======================================================================
// Pipelined GEMM core: BM=256, BN=128, BK=64, 4 waves (wave tile 128x64),
// 3-K-tile LDS ring, counted vmcnt (never 0 mid-loop), raw s_barrier,
// T2 XOR-swizzle (linear gl2lds dest + inverse-swizzled global source +
// swizzled ds_read), T5 setprio around MFMA clusters.
// LDS = 3*(256*64 + 128*64)*2B = 144 KiB -> 1 block/CU.
// ======================================================================

__device__ __forceinline__ void stage_tile(
    const char* Ab, const char* Bb, int m0, int n0, int t,
    bf16 (*As)[256][64], bf16 (*Bs)[128][64], int buf, int tid)
{
    const int srow = tid >> 3;                                   // 0..31
    const int scs  = ((tid & 7) * 16) ^ (((tid >> 3) & 7) << 4); // swizzled col byte
    #pragma unroll
    for (int j = 0; j < 8; ++j)   // A: 256 rows x 128B
        gl2lds16(Ab + (size_t)(m0 + j * 32 + srow) * 768 + t * 128 + scs,
                 (char*)&As[buf][0][0] + j * 4096 + tid * 16);
    #pragma unroll
    for (int j = 0; j < 4; ++j)   // B: 128 rows x 128B
        gl2lds16(Bb + (size_t)(n0 + j * 32 + srow) * 768 + t * 128 + scs,
                 (char*)&Bs[buf][0][0] + j * 4096 + tid * 16);
}

__device__ __forceinline__ void compute_tile(
    const bf16 (*As)[256][64], const bf16 (*Bs)[128][64], int buf,
    int wmw, int wnw, int l4, int quad, f32x4 acc[8][4])
{
    const char* Ap = (const char*)&As[buf][0][0];
    const char* Bp = (const char*)&Bs[buf][0][0];
    const int cswz = (l4 & 7) << 4;
    bf16x8 bfr[4][2];
    #pragma unroll
    for (int fn = 0; fn < 4; ++fn)
        #pragma unroll
        for (int ks = 0; ks < 2; ++ks)
            bfr[fn][ks] = *(const bf16x8*)(Bp + (wnw * 64 + fn * 16 + l4) * 128 +
                                           ((ks * 64 + quad * 16) ^ cswz));
    #pragma unroll
    for (int mh = 0; mh < 2; ++mh) {
        bf16x8 af[4][2];
        #pragma unroll
        for (int fr = 0; fr < 4; ++fr)
            #pragma unroll
            for (int ks = 0; ks < 2; ++ks)
                af[fr][ks] = *(const bf16x8*)(Ap + (wmw * 128 + mh * 64 + fr * 16 + l4) * 128 +
                                              ((ks * 64 + quad * 16) ^ cswz));
        __builtin_amdgcn_s_setprio(1);
        #pragma unroll
        for (int ks = 0; ks < 2; ++ks)
            #pragma unroll
            for (int fr = 0; fr < 4; ++fr)
                #pragma unroll
                for (int fn = 0; fn < 4; ++fn)
                    acc[mh * 4 + fr][fn] = MFMA16(af[fr][ks], bfr[fn][ks], acc[mh * 4 + fr][fn]);
        __builtin_amdgcn_s_setprio(0);
    }
}

#define GEMM_PIPE()                                                            \
    stage_tile(Ab, Bb, m0, n0, 0, As, Bs, 0, tid);                             \
    stage_tile(Ab, Bb, m0, n0, 1, As, Bs, 1, tid);                             \
    asm volatile("s_waitcnt vmcnt(12)" ::: "memory");                          \
    __builtin_amdgcn_s_barrier();                                              \
    _Pragma("unroll")                                                          \
    for (int t = 0; t < 6; ++t) {                                              \
        if (t < 4) stage_tile(Ab, Bb, m0, n0, t + 2, As, Bs, (t + 2) % 3, tid);\
        compute_tile(As, Bs, t % 3, wmw, wnw, l4, quad, acc);                  \
        if (t < 4) {                                                           \
            asm volatile("s_waitcnt vmcnt(12)" ::: "memory");                  \
            __builtin_amdgcn_s_barrier();                                      \
        } else if (t == 4) {                                                   \
            asm volatile("s_waitcnt vmcnt(0)" ::: "memory");                   \
            __builtin_amdgcn_s_barrier();                                      \
        }                                                                      \
    }

// ---------------- QKV: 65536x1152x384 ----------------
__global__ __launch_bounds__(256, 1) void qkv_gemm(
    const bf16* __restrict__ A, const bf16* __restrict__ Bt,
    bf16* __restrict__ q, bf16* __restrict__ k, bf16* __restrict__ v)
{
    __shared__ bf16 As[3][256][64];
    __shared__ bf16 Bs[3][128][64];
    const int tid = threadIdx.x, w = tid >> 6, lane = tid & 63;
    const int l4 = lane & 15, quad = lane >> 4;
    const int wmw = w >> 1, wnw = w & 1;

    // bijective XCD-chunk swizzle: nwg = 2304 = 8*288; n-tile fastest
    const int orig = blockIdx.x;
    const int id = (orig & 7) * 288 + (orig >> 3);
    const int mt_ = id / 9, nt_ = id - mt_ * 9;
    const int m0 = mt_ * 256, n0 = nt_ * 128;

    const char* Ab = (const char*)A;
    const char* Bb = (const char*)Bt;
    f32x4 acc[8][4] = {};

    GEMM_PIPE();

    // epilogue: scatter n -> (wi,h,d); m -> (b,t)
    #pragma unroll
    for (int fn = 0; fn < 4; ++fn) {
        int n = n0 + wnw * 64 + fn * 16 + l4;
        int wi = n / Csz, rem = n - wi * Csz;
        int h = rem >> 6, d = rem & 63;
        bf16* outp = wi == 0 ? q : (wi == 1 ? k : v);
        #pragma unroll
        for (int fr = 0; fr < 8; ++fr)
            #pragma unroll
            for (int r = 0; r < 4; ++r) {
                int m = m0 + wmw * 128 + fr * 16 + quad * 4 + r;
                int b = m >> 8, tt = m & 255;
                outp[(((size_t)(b * Hn + h)) * Tsz + tt) * Dh + d] = (bf16)acc[fr][fn][r];
            }
    }
}

// ---------------- proj: 65536x384x384 ----------------
__global__ __launch_bounds__(256, 1) void proj_gemm(
    const bf16* __restrict__ A, const bf16* __restrict__ Bt,
    const float* __restrict__ bias, float* __restrict__ out)
{
    __shared__ bf16 As[3][256][64];
    __shared__ bf16 Bs[3][128][64];
    const int tid = threadIdx.x, w = tid >> 6, lane = tid & 63;
    const int l4 = lane & 15, quad = lane >> 4;
    const int wmw = w >> 1, wnw = w & 1;

    // nwg = 768 = 8*96; n-tile fastest
    const int orig = blockIdx.x;
    const int id = (orig & 7) * 96 + (orig >> 3);
    const int mt_ = id / 3, nt_ = id - mt_ * 3;
    const int m0 = mt_ * 256, n0 = nt_ * 128;

    const char* Ab = (const char*)A;
    const char* Bb = (const char*)Bt;
    f32x4 acc[8][4] = {};

    GEMM_PIPE();

    #pragma unroll
    for (int fn = 0; fn < 4; ++fn) {
        int n = n0 + wnw * 64 + fn * 16 + l4;
        float bv = bias[n];
        #pragma unroll
        for (int fr = 0; fr < 8; ++fr)
            #pragma unroll
            for (int r = 0; r < 4; ++r) {
                int m = m0 + wmw * 128 + fr * 16 + quad * 4 + r;
                out[(size_t)m * Csz + n] = acc[fr][fn][r] + bv;
            }
    }
}

// ---------------- Flash attention, MFMA (exp2-domain softmax) ----------------
__global__ __launch_bounds__(256) void attn_mfma(
    const bf16* __restrict__ q, const bf16* __restrict__ k, const bf16* __restrict__ v,
    bf16* __restrict__ att)
{
    __shared__ bf16 Kl[64][72];
    __shared__ bf16 Vt[64][72];      // [d][s]
    __shared__ bf16 Pl[4][16][72];   // per-wave [qrow][s]
    const float SCL = 0.18033688f;   // 0.125 * log2(e)
    const int tid = threadIdx.x, w = tid >> 6, lane = tid & 63;
    const int l4 = lane & 15, quad = lane >> 4;

    // XCD-chunked swizzle (nblk = 6144 = 8 * 768)
    const int orig = blockIdx.x;
    const int blk = (orig & 7) * 768 + (orig >> 3);
    const int bh = blk >> 2, qt = blk & 3;
    const int b = bh / Hn, h = bh % Hn;
    const bf16* qb = q + (size_t)bh * Tsz * Dh;
    const bf16* kb = k + (size_t)bh * Tsz * Dh;
    const bf16* vb = v + (size_t)bh * Tsz * Dh;

    const int trow = qt * 64 + w * 16 + l4;
    const bf16x8 qa0 = *(const bf16x8*)&qb[trow * Dh + quad * 8];
    const bf16x8 qa1 = *(const bf16x8*)&qb[trow * Dh + 32 + quad * 8];

    f32x4 o[4] = {f32x4{0,0,0,0}, f32x4{0,0,0,0}, f32x4{0,0,0,0}, f32x4{0,0,0,0}};
    float mrun[4] = {-3.0e38f, -3.0e38f, -3.0e38f, -3.0e38f};
    float lrun[4] = {0.f, 0.f, 0.f, 0.f};

    for (int kt = 0; kt <= qt; ++kt) {
        #pragma unroll
        for (int it = 0; it < 2; ++it) {
            int idx = it * 256 + tid;
            int s = idx >> 3, d8 = (idx & 7) * 8;
            *(bf16x8*)&Kl[s][d8] = *(const bf16x8*)&kb[(kt * 64 + s) * Dh + d8];
        }
        #pragma unroll
        for (int it = 0; it < 2; ++it) {
            int idx = it * 256 + tid;
            int s = idx & 63, d8 = (idx >> 6) * 8;
            bf16x8 vv = *(const bf16x8*)&vb[(kt * 64 + s) * Dh + d8];
            #pragma unroll
            for (int j = 0; j < 8; ++j) Vt[d8 + j][s] = vv[j];
        }
        __syncthreads();

        f32x4 sc[4] = {f32x4{0,0,0,0}, f32x4{0,0,0,0}, f32x4{0,0,0,0}, f32x4{0,0,0,0}};
        #pragma unroll
        for (int nt = 0; nt < 4; ++nt) {
            bf16x8 b0 = *(const bf16x8*)&Kl[nt * 16 + l4][quad * 8];
            bf16x8 b1 = *(const bf16x8*)&Kl[nt * 16 + l4][32 + quad * 8];
            sc[nt] = MFMA16(qa0, b0, sc[nt]);
            sc[nt] = MFMA16(qa1, b1, sc[nt]);
        }

        float mnew[4], alpha[4];
        #pragma unroll
        for (int r = 0; r < 4; ++r) {
            int tg = qt * 64 + w * 16 + quad * 4 + r;
            float mx = mrun[r];
            #pragma unroll
            for (int nt = 0; nt < 4; ++nt) {
                float sv = sc[nt][r] * SCL;        // log2-domain
                int sg = kt * 64 + nt * 16 + l4;
                if (sg > tg) sv = -1.0e30f;
                sc[nt][r] = sv;
                mx = fmaxf(mx, sv);
            }
            mx = redmax16(mx);
            mnew[r] = mx;
            alpha[r] = __builtin_amdgcn_exp2f(mrun[r] - mx);
            mrun[r] = mx;
        }
        #pragma unroll
        for (int r = 0; r < 4; ++r) {
            float sm = 0.f;
            #pragma unroll
            for (int nt = 0; nt < 4; ++nt) {
                float e = __builtin_amdgcn_exp2f(sc[nt][r] - mnew[r]);
                sc[nt][r] = e;
                sm += e;
            }
            sm = redsum16(sm);
            lrun[r] = lrun[r] * alpha[r] + sm;
        }
        #pragma unroll
        for (int nt = 0; nt < 4; ++nt)
            #pragma unroll
            for (int r = 0; r < 4; ++r) o[nt][r] *= alpha[r];

        #pragma unroll
        for (int nt = 0; nt < 4; ++nt)
            #pragma unroll
            for (int r = 0; r < 4; ++r)
                Pl[w][quad * 4 + r][nt * 16 + l4] = (bf16)sc[nt][r];

        bf16x8 pa0 = *(const bf16x8*)&Pl[w][l4][quad * 8];
        bf16x8 pa1 = *(const bf16x8*)&Pl[w][l4][32 + quad * 8];
        #pragma unroll
        for (int nt = 0; nt < 4; ++nt) {
            bf16x8 vb0 = *(const bf16x8*)&Vt[nt * 16 + l4][quad * 8];
            bf16x8 vb1 = *(const bf16x8*)&Vt[nt * 16 + l4][32 + quad * 8];
            o[nt] = MFMA16(pa0, vb0, o[nt]);
            o[nt] = MFMA16(pa1, vb1, o[nt]);
        }
        __syncthreads();
    }

    #pragma unroll
    for (int r = 0; r < 4; ++r) {
        float inv = 1.f / lrun[r];
        int tg = qt * 64 + w * 16 + quad * 4 + r;
        #pragma unroll
        for (int nt = 0; nt < 4; ++nt)
            att[((size_t)(b * Tsz + tg)) * Csz + h * Dh + nt * 16 + l4] =
                (bf16)(o[nt][r] * inv);
    }
}

extern "C" void kernel_launch(void* const* d_in, const int* in_sizes, int n_in,
                              void* d_out, int out_size, void* d_ws, size_t ws_size,
                              hipStream_t stream)
{
    const float* x  = (const float*)d_in[0];
    const float* Wq = (const float*)d_in[1];
    const float* Wk = (const float*)d_in[2];
    const float* Wv = (const float*)d_in[3];
    const float* Wp = (const float*)d_in[4];
    const float* bp = (const float*)d_in[5];
    float* out = (float*)d_out;

    const size_t npe = (size_t)Bsz * Tsz * Csz;   // 25,165,824 elems
    bf16* xb    = (bf16*)d_ws;          // [65536,384]; reused as att after qkv
    bf16* att   = xb;                   // alias: xb dead once qkv_gemm completes
    bf16* q     = xb + npe;             // [B,H,T,D]
    bf16* k     = q  + npe;
    bf16* v     = k  + npe;
    bf16* Btqkv = v  + npe;             // [1152,384]
    bf16* Bpt   = Btqkv + (size_t)NQKV * Csz;   // [384,384]

    convert_x<<<npe / 2048, 256, 0, stream>>>(x, xb);
    prep_w<<<NQKV + Csz, 384, 0, stream>>>(Wq, Wk, Wv, Wp, Btqkv, Bpt);
    qkv_gemm<<<(Bsz * Tsz / 256) * (NQKV / 128), 256, 0, stream>>>(xb, Btqkv, q, k, v);
    attn_mfma<<<Bsz * Hn * 4, 256, 0, stream>>>(q, k, v, att);
    proj_gemm<<<(Bsz * Tsz / 256) * (Csz / 128), 256, 0, stream>>>(att, Bpt, bp, out);
}